// Round 1
// baseline (284.517 us; speedup 1.0000x reference)
//
#include <hip/hip_runtime.h>

#define N_NODE 80000
#define N_NET  20000
#define NE     150000
#define GROW   544   // 16 k-rows * 32 outputs + 32-wide bias row

typedef unsigned short u16;
typedef __attribute__((ext_vector_type(8))) short short8v;
typedef __attribute__((ext_vector_type(4))) float f32x4;

static __device__ __forceinline__ u16 f2bf(float f) {
  unsigned int x = __float_as_uint(f);
  x += 0x7fffu + ((x >> 16) & 1u);   // round-to-nearest-even
  return (u16)(x >> 16);
}
static __device__ __forceinline__ float bf2f(u16 u) {
  return __uint_as_float(((unsigned int)u) << 16);
}

// Build B matrices [32][GROW] bf16:
//   B[i][k*32+o] = w[(i*32+o)*16 + k]  (k < 16)
//   B[i][512+o]  = b[i*32+o]           (bias row, coefficient 1)
__global__ __launch_bounds__(256) void bmat_kernel(
    const float* __restrict__ topo_w, const float* __restrict__ topo_b,
    const float* __restrict__ geom_w, const float* __restrict__ geom_b,
    u16* __restrict__ Bt, u16* __restrict__ Bg) {
  int idx = blockIdx.x * 256 + threadIdx.x;          // 2 * 32 * 544 = 34816 exact
  int which = idx / (32 * GROW);
  int r = idx % (32 * GROW);
  int i = r / GROW, n = r % GROW;
  int k = n >> 5, o = n & 31;
  const float* w = which ? geom_w : topo_w;
  const float* b = which ? geom_b : topo_b;
  float v = (k < 16) ? w[(i * 32 + o) * 16 + k] : b[i * 32 + o];
  (which ? Bg : Bt)[i * GROW + n] = f2bf(v);
}

// G[s][n] = sum_i feat[s][i] * B[i][n].  K=32 -> one MFMA per 16x16 tile.
// One wave: 16 rows x 272 cols (17 n-tiles). 2 waves cover one row-tile.
__global__ __launch_bounds__(256) void g_precompute(
    const float* __restrict__ feat, const u16* __restrict__ Bmat,
    u16* __restrict__ G, int nrows) {
  int wave = (blockIdx.x * 256 + threadIdx.x) >> 6;
  int lane = threadIdx.x & 63;
  int tile = wave >> 1;
  int half = wave & 1;
  if (tile * 16 >= nrows) return;
  int row = lane & 15;          // A row within tile / B+D column
  int k0  = (lane >> 4) * 8;    // 8 consecutive K elements per lane
  int s0  = tile * 16;

  const float* ap = feat + (size_t)(s0 + row) * 32 + k0;
  float4 a0 = *(const float4*)ap;
  float4 a1 = *(const float4*)(ap + 4);
  short8v af;
  af[0]=(short)f2bf(a0.x); af[1]=(short)f2bf(a0.y); af[2]=(short)f2bf(a0.z); af[3]=(short)f2bf(a0.w);
  af[4]=(short)f2bf(a1.x); af[5]=(short)f2bf(a1.y); af[6]=(short)f2bf(a1.z); af[7]=(short)f2bf(a1.w);

  for (int t = 0; t < 17; ++t) {
    int n0 = (half * 17 + t) * 16;
    const u16* bp = Bmat + (size_t)k0 * GROW + n0 + row;
    short8v bfr;
#pragma unroll
    for (int j = 0; j < 8; ++j) bfr[j] = (short)bp[(size_t)j * GROW];
    f32x4 c = {0.f, 0.f, 0.f, 0.f};
    c = __builtin_amdgcn_mfma_f32_16x16x32_bf16(af, bfr, c, 0, 0, 0);
    // D: col = lane&15, row = (lane>>4)*4 + r   [verified layout, m89]
    u16* gp = G + (size_t)(s0 + (lane >> 4) * 4) * GROW + n0 + row;
#pragma unroll
    for (int r4 = 0; r4 < 4; ++r4) gp[(size_t)r4 * GROW] = f2bf(c[r4]);
  }
}

__global__ __launch_bounds__(256) void deg_kernel(
    const int* __restrict__ pins_src, const int* __restrict__ pins_dst,
    const int* __restrict__ pinned_dst, const int* __restrict__ near_dst,
    float* __restrict__ deg_out, float* __restrict__ deg_in,
    float* __restrict__ deg_p, float* __restrict__ deg_n) {
  int e = blockIdx.x * 256 + threadIdx.x;
  if (e >= NE) return;
  atomicAdd(deg_out + pins_src[e], 1.0f);
  atomicAdd(deg_in  + pins_dst[e], 1.0f);
  atomicAdd(deg_p   + pinned_dst[e], 1.0f);
  atomicAdd(deg_n   + near_dst[e], 1.0f);
}

// GraphConv message: agg[dst] += node_feat[src] * rsqrt(max(deg_out[src],1))
__global__ __launch_bounds__(256) void pins_edge_kernel(
    const float* __restrict__ node_feat, const int* __restrict__ src,
    const int* __restrict__ dst, const float* __restrict__ deg_out,
    float* __restrict__ agg) {
  int gid = blockIdx.x * 256 + threadIdx.x;
  int e = gid >> 5;
  if (e >= NE) return;
  int o = gid & 31;
  int s = src[e], d = dst[e];
  float ns = rsqrtf(fmaxf(deg_out[s], 1.0f));
  atomicAdd(agg + (size_t)d * 32 + o, node_feat[(size_t)s * 32 + o] * ns);
}

// NNConv message via precomputed G: msg[o] = G[s][512+o] + sum_k pf[e][k]*G[s][k*32+o]
__global__ __launch_bounds__(256) void nnconv_edge_kernel(
    const u16* __restrict__ G, const float* __restrict__ efeat,
    const int* __restrict__ src, const int* __restrict__ dst,
    float* __restrict__ acc) {
  int gid = blockIdx.x * 256 + threadIdx.x;
  int e = gid >> 5;
  if (e >= NE) return;
  int o = gid & 31;
  int s = src[e], d = dst[e];
  const u16* g = G + (size_t)s * GROW;
  const float4* pf = (const float4*)(efeat + (size_t)e * 16);
  float4 p0 = pf[0], p1 = pf[1], p2 = pf[2], p3 = pf[3];
  float pv[16] = {p0.x,p0.y,p0.z,p0.w, p1.x,p1.y,p1.z,p1.w,
                  p2.x,p2.y,p2.z,p2.w, p3.x,p3.y,p3.z,p3.w};
  float m = bf2f(g[512 + o]);
#pragma unroll
  for (int k = 0; k < 16; ++k) m += pv[k] * bf2f(g[k * 32 + o]);
  atomicAdd(acc + (size_t)d * 32 + o, m);
}

// net_out = rsqrt(max(deg_in,1)) * (agg @ gc_w) + gc_b
__global__ __launch_bounds__(256) void net_out_kernel(
    const float* __restrict__ agg, const float* __restrict__ deg_in,
    const float* __restrict__ gc_w, const float* __restrict__ gc_b,
    float* __restrict__ out) {
  int gid = blockIdx.x * 256 + threadIdx.x;
  int m = gid >> 5;
  if (m >= N_NET) return;
  int o = gid & 31;
  float nd = rsqrtf(fmaxf(deg_in[m], 1.0f));
  const float* ag = agg + (size_t)m * 32;
  float a = 0.f;
#pragma unroll
  for (int j = 0; j < 32; ++j) a += ag[j] * gc_w[j * 32 + o];
  out[(size_t)N_NODE * 32 + (size_t)m * 32 + o] = a * nd + gc_b[o];
}

// node_out = max(acc_p/deg_p + pinned_b, acc_n/deg_n + near_b)
__global__ __launch_bounds__(256) void node_out_kernel(
    const float* __restrict__ acc_p, const float* __restrict__ acc_n,
    const float* __restrict__ deg_p, const float* __restrict__ deg_n,
    const float* __restrict__ pinned_b, const float* __restrict__ near_b,
    float* __restrict__ out) {
  int gid = blockIdx.x * 256 + threadIdx.x;
  int v = gid >> 5;
  if (v >= N_NODE) return;
  int o = gid & 31;
  float ap = acc_p[gid] / fmaxf(deg_p[v], 1.0f) + pinned_b[o];
  float an = acc_n[gid] / fmaxf(deg_n[v], 1.0f) + near_b[o];
  out[gid] = fmaxf(ap, an);
}

extern "C" void kernel_launch(void* const* d_in, const int* in_sizes, int n_in,
                              void* d_out, int out_size, void* d_ws, size_t ws_size,
                              hipStream_t stream) {
  const float* node_feat = (const float*)d_in[0];
  const float* net_feat  = (const float*)d_in[1];
  const float* pin_feat  = (const float*)d_in[2];
  const float* edge_feat = (const float*)d_in[3];
  const float* topo_w    = (const float*)d_in[4];
  const float* topo_b    = (const float*)d_in[5];
  const float* geom_w    = (const float*)d_in[6];
  const float* geom_b    = (const float*)d_in[7];
  const float* gc_w      = (const float*)d_in[8];
  const float* gc_b      = (const float*)d_in[9];
  const float* pinned_b  = (const float*)d_in[10];
  const float* near_b    = (const float*)d_in[11];
  const int* pins_src    = (const int*)d_in[12];
  const int* pins_dst    = (const int*)d_in[13];
  const int* pinned_src  = (const int*)d_in[14];
  const int* pinned_dst  = (const int*)d_in[15];
  const int* near_src    = (const int*)d_in[16];
  const int* near_dst    = (const int*)d_in[17];

  char* ws = (char*)d_ws;
  float* acc_p   = (float*)ws;            // 2,560,000 f32
  float* acc_n   = acc_p + 2560000;       // 2,560,000
  float* agg     = acc_n + 2560000;       //   640,000
  float* deg_out = agg + 640000;          //    80,000
  float* deg_in  = deg_out + 80000;       //    20,000
  float* deg_p   = deg_in + 20000;        //    80,000
  float* deg_n   = deg_p + 80000;         //    80,000
  size_t zero_bytes = (size_t)6020000 * 4;
  size_t off = (zero_bytes + 255) & ~(size_t)255;
  u16* G_net  = (u16*)(ws + off);  off += (size_t)N_NET * GROW * 2;
  off = (off + 255) & ~(size_t)255;
  u16* G_node = (u16*)(ws + off);  off += (size_t)N_NODE * GROW * 2;
  off = (off + 255) & ~(size_t)255;
  u16* Bt = (u16*)(ws + off);      off += (size_t)32 * GROW * 2;
  u16* Bg = (u16*)(ws + off);

  hipMemsetAsync(d_ws, 0, zero_bytes, stream);
  bmat_kernel<<<136, 256, 0, stream>>>(topo_w, topo_b, geom_w, geom_b, Bt, Bg);
  g_precompute<<<625, 256, 0, stream>>>(net_feat, Bt, G_net, N_NET);     // 1250 tiles * 2 waves
  g_precompute<<<2500, 256, 0, stream>>>(node_feat, Bg, G_node, N_NODE); // 5000 tiles * 2 waves
  deg_kernel<<<(NE + 255) / 256, 256, 0, stream>>>(pins_src, pins_dst, pinned_dst, near_dst,
                                                   deg_out, deg_in, deg_p, deg_n);
  pins_edge_kernel<<<NE * 32 / 256, 256, 0, stream>>>(node_feat, pins_src, pins_dst, deg_out, agg);
  nnconv_edge_kernel<<<NE * 32 / 256, 256, 0, stream>>>(G_net, pin_feat, pinned_src, pinned_dst, acc_p);
  nnconv_edge_kernel<<<NE * 32 / 256, 256, 0, stream>>>(G_node, edge_feat, near_src, near_dst, acc_n);
  net_out_kernel<<<N_NET * 32 / 256, 256, 0, stream>>>(agg, deg_in, gc_w, gc_b, (float*)d_out);
  node_out_kernel<<<N_NODE * 32 / 256, 256, 0, stream>>>(acc_p, acc_n, deg_p, deg_n,
                                                         pinned_b, near_b, (float*)d_out);
}